// Round 7
// baseline (657.558 us; speedup 1.0000x reference)
//
#include <hip/hip_runtime.h>
#include <cstdint>
#include <cstddef>

// ---------------------------------------------------------------------------
// LASAGE R7:
//   - A-stationary MFMA GEMM: block owns 64 rows; stages [A1row|A2row]
//     (K'=512 bf16, 66.5 KB LDS, 2 blocks/CU) ONCE; loops ALL output-column
//     tiles inside the block with weights loaded global->VGPR (L2-hot,
//     pre-concatenated per layer). Fixes R6's A-re-read (y-blocks pulled
//     ~205 MB from L3 for the mid conv).
//   - L0+L1 merged into one dispatch; final conv computes Z=hm@Wlo (bf16)
//     and out=hm@Wro+bo (fp32) in one dispatch over shared A.
//   - Aggregation: R4's wave-per-node 256-col bf16 gather, unrolled x2.
//   - Buffers: xc bf16[N,256] over d_in[0]; h bf16 -> d_in[1]; hm bf16 ->
//     d_in[0]; agg/Z/weights in ws; out = final GEMM + agg64_add.
// ---------------------------------------------------------------------------

typedef __attribute__((ext_vector_type(8))) short short8;   // 8 x bf16
typedef __attribute__((ext_vector_type(4))) float f32x4;    // MFMA acc

__device__ __forceinline__ ushort f2bf(float f) {
    unsigned u = __float_as_uint(f);
    u += 0x7fffu + ((u >> 16) & 1u);   // round-to-nearest-even
    return (ushort)(u >> 16);
}
__device__ __forceinline__ float bf2f(ushort u) {
    return __uint_as_float((unsigned)u << 16);
}

// ---------------- CSR construction (verified R3-R6) ----------------

__global__ void deg_kernel(const int* __restrict__ dst, int* __restrict__ deg, int E) {
    int i = blockIdx.x * blockDim.x + threadIdx.x;
    if (i < E) atomicAdd(&deg[dst[i]], 1);
}

__global__ void chunk_sum_kernel(const int* __restrict__ deg,
                                 int* __restrict__ csum, int N, int CH) {
    int t = blockIdx.x * blockDim.x + threadIdx.x;
    int beg = t * CH, end = min(beg + CH, N);
    int s = 0;
    for (int i = beg; i < end; ++i) s += deg[i];
    csum[t] = s;
}

__global__ void scan1024_kernel(const int* __restrict__ csum, int* __restrict__ coff) {
    __shared__ int sh[1024];
    int t = threadIdx.x;
    int v0 = csum[t];
    sh[t] = v0;
    __syncthreads();
    for (int off = 1; off < 1024; off <<= 1) {
        int v = (t >= off) ? sh[t - off] : 0;
        __syncthreads();
        sh[t] += v;
        __syncthreads();
    }
    coff[t] = sh[t] - v0;
}

__global__ void rowptr_kernel(const int* __restrict__ deg, const int* __restrict__ coff,
                              int* __restrict__ rowptr, int N, int CH, int E) {
    int t = blockIdx.x * blockDim.x + threadIdx.x;
    int beg = t * CH, end = min(beg + CH, N);
    int run = coff[t];
    for (int i = beg; i < end; ++i) { rowptr[i] = run; run += deg[i]; }
    if (t == 0) rowptr[N] = E;
}

__global__ void scatter_kernel(const int* __restrict__ src, const int* __restrict__ dst,
                               const int* __restrict__ rowptr, int* __restrict__ cursor,
                               int* __restrict__ col, int E) {
    int i = blockIdx.x * blockDim.x + threadIdx.x;
    if (i < E) {
        int d = dst[i];
        int pos = atomicAdd(&cursor[d], 1);
        col[rowptr[d] + pos] = src[i];
    }
}

// ---------------- conversions ----------------

// xc[n][0:128]=bf16(x0[n]), xc[n][128:256]=bf16(x1[n]); xc ALIASES x0's buffer.
__global__ void conv_x_kernel(const float* x0, const float* x1, ushort* xc, int N) {
    int gid = blockIdx.x * blockDim.x + threadIdx.x;
    int w = gid >> 6, lane = gid & 63;
    if (w >= N) return;
    float2 a = *((const float2*)(x0 + (size_t)w * 128) + lane);
    float2 b = *((const float2*)(x1 + (size_t)w * 128) + lane);
    ushort2 ua; ua.x = f2bf(a.x); ua.y = f2bf(a.y);
    ushort2 ub; ub.x = f2bf(b.x); ub.y = f2bf(b.y);
    *((ushort2*)(xc + (size_t)w * 256) + lane) = ua;
    *((ushort2*)(xc + (size_t)w * 256 + 128) + lane) = ub;
}

// Build per-layer concatenated bf16 weight tensors, [n][k'] k-major:
//  Wcat1 [256][256]: n<128: [Wl0(:,n) | Wr0(:,n)]; n>=128: [Wl1 | Wr1] (n-128)
//  Wcat2 [256][512]: [Wlm(:,n) | Wrm(:,n)]
//  Wcat3 [128][256]: n<64: Wlo(:,n); n>=64: Wro(:,n-64)
//  bcat01[256] fp32 = [b0 | b1]
__global__ void conv_w_all_kernel(
    const float* __restrict__ Wl0, const float* __restrict__ Wr0,
    const float* __restrict__ Wl1, const float* __restrict__ Wr1,
    const float* __restrict__ Wlm, const float* __restrict__ Wrm,
    const float* __restrict__ Wlo, const float* __restrict__ Wro,
    const float* __restrict__ b0, const float* __restrict__ b1,
    ushort* __restrict__ Wcat1, ushort* __restrict__ Wcat2,
    ushort* __restrict__ Wcat3, float* __restrict__ bcat01) {
    int idx = blockIdx.x * blockDim.x + threadIdx.x;
    if (idx < 65536) {                       // Wcat1
        int n = idx >> 8, k = idx & 255;
        int half = n >> 7, nl = n & 127;
        const float* Wl = half ? Wl1 : Wl0;
        const float* Wr = half ? Wr1 : Wr0;
        float v = (k < 128) ? Wl[(size_t)k * 128 + nl]
                            : Wr[(size_t)(k - 128) * 128 + nl];
        Wcat1[idx] = f2bf(v);
    } else if (idx < 65536 + 131072) {       // Wcat2
        int i2 = idx - 65536;
        int n = i2 >> 9, k = i2 & 511;
        float v = (k < 256) ? Wlm[(size_t)k * 256 + n]
                            : Wrm[(size_t)(k - 256) * 256 + n];
        Wcat2[i2] = f2bf(v);
    } else if (idx < 65536 + 131072 + 32768) {  // Wcat3
        int i3 = idx - (65536 + 131072);
        int n = i3 >> 8, k = i3 & 255;
        float v = (n < 64) ? Wlo[(size_t)k * 64 + n]
                           : Wro[(size_t)k * 64 + (n - 64)];
        Wcat3[i3] = f2bf(v);
    } else if (idx < 65536 + 131072 + 32768 + 256) {  // bcat01
        int i4 = idx - (65536 + 131072 + 32768);
        bcat01[i4] = (i4 < 128) ? b0[i4] : b1[i4 - 128];
    }
}

// ---------------- aggregation: wave per node, 256 bf16 cols, unroll x2 ----

__global__ void agg_bf16_kernel(const ushort* __restrict__ src,
                                const int* __restrict__ rowptr,
                                const int* __restrict__ col,
                                ushort* __restrict__ outt, int N) {
    int gid = blockIdx.x * blockDim.x + threadIdx.x;
    int w = gid >> 6, lane = gid & 63;
    if (w >= N) return;
    int beg = rowptr[w], end = rowptr[w + 1];
    float s0 = 0.f, s1 = 0.f, s2 = 0.f, s3 = 0.f;
    int k = beg;
    for (; k + 2 <= end; k += 2) {
        int ca = col[k], cb = col[k + 1];
        ushort4 va = *((const ushort4*)(src + (size_t)ca * 256) + lane);
        ushort4 vb = *((const ushort4*)(src + (size_t)cb * 256) + lane);
        s0 += bf2f(va.x) + bf2f(vb.x);
        s1 += bf2f(va.y) + bf2f(vb.y);
        s2 += bf2f(va.z) + bf2f(vb.z);
        s3 += bf2f(va.w) + bf2f(vb.w);
    }
    if (k < end) {
        ushort4 v = *((const ushort4*)(src + (size_t)col[k] * 256) + lane);
        s0 += bf2f(v.x); s1 += bf2f(v.y); s2 += bf2f(v.z); s3 += bf2f(v.w);
    }
    float inv = 1.0f / (float)max(end - beg, 1);
    ushort4 o;
    o.x = f2bf(s0 * inv); o.y = f2bf(s1 * inv);
    o.z = f2bf(s2 * inv); o.w = f2bf(s3 * inv);
    *((ushort4*)(outt + (size_t)w * 256) + lane) = o;
}

// ---------------- agg of 64-col bf16 table, accumulate into fp32 out ------

__global__ void agg64_add_kernel(const ushort* __restrict__ Z,
                                 const int* __restrict__ rowptr,
                                 const int* __restrict__ col,
                                 float* __restrict__ out, int N) {
    int gid = blockIdx.x * blockDim.x + threadIdx.x;
    int w = gid >> 6, lane = gid & 63;
    if (w >= N) return;
    int beg = rowptr[w], end = rowptr[w + 1];
    float sa = 0.f, sb = 0.f;
    int k = beg;
    for (; k + 2 <= end; k += 2) {
        sa += bf2f(Z[(size_t)col[k] * 64 + lane]);
        sb += bf2f(Z[(size_t)col[k + 1] * 64 + lane]);
    }
    if (k < end) sa += bf2f(Z[(size_t)col[k] * 64 + lane]);
    float inv = 1.0f / (float)max(end - beg, 1);
    out[(size_t)w * 64 + lane] += (sa + sb) * inv;
}

// ---------------- A-stationary MFMA GEMM ----------------
// Block = 256 thr = 4 waves, owns 64 rows. Stages [A1row|A2row] (KT bf16)
// into LDS once (1 barrier), then loops y over ALL output 64-col tiles with
// weights loaded global->VGPR (L2-hot). Wave w owns rows w*16..w*16+15.
// MODE 0 (L0+L1): KT=512, NY=4, W=Wcat1[256][256]; y-half selects 128-k
//   windows: seg1 lds=(y>>1)*128 <-> Wk 0..128 (agg), seg2 lds=256+(y>>1)*128
//   <-> Wk 128..256 (self). bf16 store + relu + bias.
// MODE 1 (mid): KT=512, NY=4, W=Wcat2[256][512], one seg (lds k' == W k').
// MODE 2 (final): KT=256 (A1 only), NY=2, W=Wcat3[128][256];
//   y=0 -> D bf16 (Z), no bias; y=1 -> D2 fp32 + bias.
// LDS row stride KT+8: a-frag b128 reads spread (lr+lq)%8 -> 2-way, free.
template <int MODE>
__global__ __launch_bounds__(256) void rs_gemm_kernel(
    const ushort* __restrict__ A1, const ushort* __restrict__ A2, int lda,
    const ushort* __restrict__ W, const float* __restrict__ bias,
    ushort* __restrict__ D, float* __restrict__ D2, int M) {
    constexpr int KT = (MODE == 2) ? 256 : 512;
    constexpr int PK = KT + 8;
    constexpr int NY = (MODE == 2) ? 2 : 4;
    constexpr int LDW = (MODE == 1) ? 512 : 256;
    __shared__ __align__(16) ushort As[64 * PK];

    int tid = threadIdx.x;
    int m0 = blockIdx.x * 64;

    {   // stage 64 rows x KT
        int r = tid >> 2;
        int m = m0 + r;
        int c0 = (tid & 3) * 8;
        bool ok = m < M;
        const ushort* a1 = A1 + (size_t)m * lda;
#pragma unroll
        for (int c = 0; c < 256; c += 32) {
            float4 v = make_float4(0.f, 0.f, 0.f, 0.f);
            if (ok) v = *(const float4*)(a1 + c + c0);
            *(float4*)&As[r * PK + c + c0] = v;
        }
        if (MODE != 2) {
            const ushort* a2 = A2 + (size_t)m * lda;
#pragma unroll
            for (int c = 0; c < 256; c += 32) {
                float4 v = make_float4(0.f, 0.f, 0.f, 0.f);
                if (ok) v = *(const float4*)(a2 + c + c0);
                *(float4*)&As[r * PK + 256 + c + c0] = v;
            }
        }
    }
    __syncthreads();

    int wave = tid >> 6, lane = tid & 63;
    int lr = lane & 15, lq = lane >> 4;
    int arow = (wave * 16 + lr) * PK;

    for (int y = 0; y < NY; ++y) {
        f32x4 acc[4];
#pragma unroll
        for (int j = 0; j < 4; ++j) acc[j] = (f32x4){0.f, 0.f, 0.f, 0.f};

        const ushort* wrow[4];
#pragma unroll
        for (int nt = 0; nt < 4; ++nt)
            wrow[nt] = W + (size_t)(y * 64 + nt * 16 + lr) * LDW;

        if (MODE == 0) {
            int half = y >> 1;
#pragma unroll
            for (int k = 0; k < 128; k += 32) {   // agg segment
                short8 a = *(const short8*)&As[arow + half * 128 + k + lq * 8];
#pragma unroll
                for (int nt = 0; nt < 4; ++nt) {
                    short8 b = *(const short8*)(wrow[nt] + k + lq * 8);
                    acc[nt] = __builtin_amdgcn_mfma_f32_16x16x32_bf16(a, b, acc[nt], 0, 0, 0);
                }
            }
#pragma unroll
            for (int k = 0; k < 128; k += 32) {   // self segment
                short8 a = *(const short8*)&As[arow + 256 + half * 128 + k + lq * 8];
#pragma unroll
                for (int nt = 0; nt < 4; ++nt) {
                    short8 b = *(const short8*)(wrow[nt] + 128 + k + lq * 8);
                    acc[nt] = __builtin_amdgcn_mfma_f32_16x16x32_bf16(a, b, acc[nt], 0, 0, 0);
                }
            }
        } else {
            constexpr int KS = (MODE == 1) ? 512 : 256;
#pragma unroll
            for (int k = 0; k < KS; k += 32) {
                short8 a = *(const short8*)&As[arow + k + lq * 8];
#pragma unroll
                for (int nt = 0; nt < 4; ++nt) {
                    short8 b = *(const short8*)(wrow[nt] + k + lq * 8);
                    acc[nt] = __builtin_amdgcn_mfma_f32_16x16x32_bf16(a, b, acc[nt], 0, 0, 0);
                }
            }
        }

        // epilogue: C/D layout col = lane&15, row = (lane>>4)*4 + reg  [m89]
#pragma unroll
        for (int nt = 0; nt < 4; ++nt) {
            int c = nt * 16 + lr;           // column within this y-tile
            int ng = y * 64 + c;            // global output column
#pragma unroll
            for (int r = 0; r < 4; ++r) {
                int m = m0 + wave * 16 + lq * 4 + r;
                if (m >= M) continue;
                float v = acc[nt][r];
                if (MODE == 2) {
                    if (y == 0) D[(size_t)m * 64 + c] = f2bf(v);
                    else        D2[(size_t)m * 64 + c] = v + bias[c];
                } else {
                    v = fmaxf(v + bias[ng], 0.f);
                    D[(size_t)m * 256 + ng] = f2bf(v);
                }
            }
        }
    }
}

// ---------------------------------------------------------------------------

extern "C" void kernel_launch(void* const* d_in, const int* in_sizes, int n_in,
                              void* d_out, int out_size, void* d_ws, size_t ws_size,
                              hipStream_t stream) {
    const float* x0 = (const float*)d_in[0];
    const float* x1 = (const float*)d_in[1];
    const int* ei = (const int*)d_in[2];  // integer inputs arrive as int32
    const float* Wl0 = (const float*)d_in[3];
    const float* Wr0 = (const float*)d_in[4];
    const float* b0 = (const float*)d_in[5];
    const float* Wl1 = (const float*)d_in[6];
    const float* Wr1 = (const float*)d_in[7];
    const float* b1 = (const float*)d_in[8];
    const float* Wlm = (const float*)d_in[9];
    const float* Wrm = (const float*)d_in[10];
    const float* bm = (const float*)d_in[11];
    const float* Wlo = (const float*)d_in[12];
    const float* Wro = (const float*)d_in[13];
    const float* bo = (const float*)d_in[14];

    const int N = in_sizes[0] / 128;
    const int E = in_sizes[2] / 2;
    const int* srcI = ei;
    const int* dstI = ei + E;

    // activation buffers aliased onto the (restored-each-call) input buffers
    ushort* xc  = (ushort*)d_in[0];  // [N,256] bf16 over x0's fp32 buf
    ushort* hb  = (ushort*)d_in[1];  // [N,256] bf16 over x1's buf
    ushort* hmb = (ushort*)d_in[0];  // [N,256] bf16 over xc (dead post-L0/L1)
    float* out = (float*)d_out;

    // ---- ws carve ----
    char* ws = (char*)d_ws;
    size_t used = 0;
    auto carve = [&](size_t bytes) {
        char* p = ws + used;
        used += (bytes + 63) & ~(size_t)63;
        return p;
    };
    int* deg = (int*)carve((size_t)2 * N * 4);
    int* cursor = deg + N;
    int* csum = (int*)carve(1024 * 4);
    int* coff = (int*)carve(1024 * 4);
    int* rowptr = (int*)carve((size_t)(N + 1) * 4);
    int* col = (int*)carve((size_t)E * 4);
    ushort* aggb = (ushort*)carve((size_t)N * 256 * 2);
    ushort* Zb   = (ushort*)carve((size_t)N * 64 * 2);
    ushort* Wcat1 = (ushort*)carve(256 * 256 * 2);
    ushort* Wcat2 = (ushort*)carve(256 * 512 * 2);
    ushort* Wcat3 = (ushort*)carve(128 * 256 * 2);
    float* bcat01 = (float*)carve(256 * 4);
    if (used > ws_size) return;  // fail clean, not with a mem fault

    const int CH = (N + 1023) / 1024;
    const int eb = (E + 255) / 256;
    const int ab = (N * 64 + 255) / 256;   // wave-per-node grid
    const int gb = (N + 63) / 64;          // GEMM 64-row blocks
    const ushort* UN = nullptr;

    // ---- CSR ----
    hipMemsetAsync(deg, 0, (size_t)2 * N * 4, stream);
    deg_kernel<<<eb, 256, 0, stream>>>(dstI, deg, E);
    chunk_sum_kernel<<<4, 256, 0, stream>>>(deg, csum, N, CH);
    scan1024_kernel<<<1, 1024, 0, stream>>>(csum, coff);
    rowptr_kernel<<<4, 256, 0, stream>>>(deg, coff, rowptr, N, CH, E);
    scatter_kernel<<<eb, 256, 0, stream>>>(srcI, dstI, rowptr, cursor, col, E);

    // ---- conversions ----
    conv_x_kernel<<<ab, 256, 0, stream>>>(x0, x1, xc, N);
    conv_w_all_kernel<<<(65536 + 131072 + 32768 + 256 + 255) / 256, 256, 0, stream>>>(
        Wl0, Wr0, Wl1, Wr1, Wlm, Wrm, Wlo, Wro, b0, b1,
        Wcat1, Wcat2, Wcat3, bcat01);

    // ---- layer 0+1: h = relu([agg(xc)|xc] @ Wcat + bcat), merged ----
    agg_bf16_kernel<<<ab, 256, 0, stream>>>(xc, rowptr, col, aggb, N);
    rs_gemm_kernel<0><<<gb, 256, 0, stream>>>(
        aggb, xc, 256, Wcat1, bcat01, hb, nullptr, N);

    // ---- middle conv: hm = relu([agg(h)|h] @ Wcat2 + bm) ----
    agg_bf16_kernel<<<ab, 256, 0, stream>>>(hb, rowptr, col, aggb, N);
    rs_gemm_kernel<1><<<gb, 256, 0, stream>>>(
        aggb, hb, 256, Wcat2, bm, hmb, nullptr, N);

    // ---- final conv (commuted): Z = hm@Wlo (bf16), out = hm@Wro + bo ----
    rs_gemm_kernel<2><<<gb, 256, 0, stream>>>(
        hmb, UN, 256, Wcat3, bo, Zb, out, N);
    agg64_add_kernel<<<ab, 256, 0, stream>>>(Zb, rowptr, col, out, N);
}

// Round 8
// 487.659 us; speedup vs baseline: 1.3484x; 1.3484x over previous
//
#include <hip/hip_runtime.h>
#include <cstdint>
#include <cstddef>

// ---------------------------------------------------------------------------
// LASAGE R8: A-streaming / W-in-LDS GEMM (fixes R7's inverted operand placement).
//   - Block = 128-row strip of A. W staged to LDS in 64KB chunks (128n x 256k,
//     67.6KB -> 2 blocks/CU); K-loop: B from LDS (b128), A global->VGPR with
//     1-step prefetch, 16 MFMA per k-step. Fully unrolled (K1/K2 templated).
//   - L0+L1: grid.y = layer (disjoint A cols -> A read once).
//     Mid: grid.y = 2 n-halves (A read 2x; 2nd pass L3-hot).
//     Final: 1 pass, cols 0..63 -> Z bf16, 64..127 -> out fp32 + bias.
//   - Aggregation unchanged (R4/R7 wave-per-node, unroll x2).
//   - Buffers: xc bf16[N,256] over d_in[0]; h -> d_in[1]; hm -> d_in[0];
//     agg/Z/weights in ws; out = final GEMM + agg64_add.
// ---------------------------------------------------------------------------

typedef __attribute__((ext_vector_type(8))) short short8;   // 8 x bf16
typedef __attribute__((ext_vector_type(4))) float f32x4;    // MFMA acc

__device__ __forceinline__ ushort f2bf(float f) {
    unsigned u = __float_as_uint(f);
    u += 0x7fffu + ((u >> 16) & 1u);   // round-to-nearest-even
    return (ushort)(u >> 16);
}
__device__ __forceinline__ float bf2f(ushort u) {
    return __uint_as_float((unsigned)u << 16);
}

// ---------------- CSR construction (verified R3-R7) ----------------

__global__ void deg_kernel(const int* __restrict__ dst, int* __restrict__ deg, int E) {
    int i = blockIdx.x * blockDim.x + threadIdx.x;
    if (i < E) atomicAdd(&deg[dst[i]], 1);
}

__global__ void chunk_sum_kernel(const int* __restrict__ deg,
                                 int* __restrict__ csum, int N, int CH) {
    int t = blockIdx.x * blockDim.x + threadIdx.x;
    int beg = t * CH, end = min(beg + CH, N);
    int s = 0;
    for (int i = beg; i < end; ++i) s += deg[i];
    csum[t] = s;
}

__global__ void scan1024_kernel(const int* __restrict__ csum, int* __restrict__ coff) {
    __shared__ int sh[1024];
    int t = threadIdx.x;
    int v0 = csum[t];
    sh[t] = v0;
    __syncthreads();
    for (int off = 1; off < 1024; off <<= 1) {
        int v = (t >= off) ? sh[t - off] : 0;
        __syncthreads();
        sh[t] += v;
        __syncthreads();
    }
    coff[t] = sh[t] - v0;
}

__global__ void rowptr_kernel(const int* __restrict__ deg, const int* __restrict__ coff,
                              int* __restrict__ rowptr, int N, int CH, int E) {
    int t = blockIdx.x * blockDim.x + threadIdx.x;
    int beg = t * CH, end = min(beg + CH, N);
    int run = coff[t];
    for (int i = beg; i < end; ++i) { rowptr[i] = run; run += deg[i]; }
    if (t == 0) rowptr[N] = E;
}

__global__ void scatter_kernel(const int* __restrict__ src, const int* __restrict__ dst,
                               const int* __restrict__ rowptr, int* __restrict__ cursor,
                               int* __restrict__ col, int E) {
    int i = blockIdx.x * blockDim.x + threadIdx.x;
    if (i < E) {
        int d = dst[i];
        int pos = atomicAdd(&cursor[d], 1);
        col[rowptr[d] + pos] = src[i];
    }
}

// ---------------- conversions ----------------

// xc[n][0:128]=bf16(x0[n]), xc[n][128:256]=bf16(x1[n]); xc ALIASES x0's buffer.
__global__ void conv_x_kernel(const float* x0, const float* x1, ushort* xc, int N) {
    int gid = blockIdx.x * blockDim.x + threadIdx.x;
    int w = gid >> 6, lane = gid & 63;
    if (w >= N) return;
    float2 a = *((const float2*)(x0 + (size_t)w * 128) + lane);
    float2 b = *((const float2*)(x1 + (size_t)w * 128) + lane);
    ushort2 ua; ua.x = f2bf(a.x); ua.y = f2bf(a.y);
    ushort2 ub; ub.x = f2bf(b.x); ub.y = f2bf(b.y);
    *((ushort2*)(xc + (size_t)w * 256) + lane) = ua;
    *((ushort2*)(xc + (size_t)w * 256 + 128) + lane) = ub;
}

// Build per-layer concatenated bf16 weight tensors, [n][k'] k-major:
//  Wcat1 [256][256]: n<128: [Wl0(:,n) | Wr0(:,n)]; n>=128: [Wl1 | Wr1] (n-128)
//  Wcat2 [256][512]: [Wlm(:,n) | Wrm(:,n)]
//  Wcat3 [128][256]: n<64: Wlo(:,n); n>=64: Wro(:,n-64)
//  bcat01[256] fp32 = [b0 | b1]
__global__ void conv_w_all_kernel(
    const float* __restrict__ Wl0, const float* __restrict__ Wr0,
    const float* __restrict__ Wl1, const float* __restrict__ Wr1,
    const float* __restrict__ Wlm, const float* __restrict__ Wrm,
    const float* __restrict__ Wlo, const float* __restrict__ Wro,
    const float* __restrict__ b0, const float* __restrict__ b1,
    ushort* __restrict__ Wcat1, ushort* __restrict__ Wcat2,
    ushort* __restrict__ Wcat3, float* __restrict__ bcat01) {
    int idx = blockIdx.x * blockDim.x + threadIdx.x;
    if (idx < 65536) {                       // Wcat1
        int n = idx >> 8, k = idx & 255;
        int half = n >> 7, nl = n & 127;
        const float* Wl = half ? Wl1 : Wl0;
        const float* Wr = half ? Wr1 : Wr0;
        float v = (k < 128) ? Wl[(size_t)k * 128 + nl]
                            : Wr[(size_t)(k - 128) * 128 + nl];
        Wcat1[idx] = f2bf(v);
    } else if (idx < 65536 + 131072) {       // Wcat2
        int i2 = idx - 65536;
        int n = i2 >> 9, k = i2 & 511;
        float v = (k < 256) ? Wlm[(size_t)k * 256 + n]
                            : Wrm[(size_t)(k - 256) * 256 + n];
        Wcat2[i2] = f2bf(v);
    } else if (idx < 65536 + 131072 + 32768) {  // Wcat3
        int i3 = idx - (65536 + 131072);
        int n = i3 >> 8, k = i3 & 255;
        float v = (n < 64) ? Wlo[(size_t)k * 64 + n]
                           : Wro[(size_t)k * 64 + (n - 64)];
        Wcat3[i3] = f2bf(v);
    } else if (idx < 65536 + 131072 + 32768 + 256) {  // bcat01
        int i4 = idx - (65536 + 131072 + 32768);
        bcat01[i4] = (i4 < 128) ? b0[i4] : b1[i4 - 128];
    }
}

// ---------------- aggregation: wave per node, 256 bf16 cols, unroll x2 ----

__global__ void agg_bf16_kernel(const ushort* __restrict__ src,
                                const int* __restrict__ rowptr,
                                const int* __restrict__ col,
                                ushort* __restrict__ outt, int N) {
    int gid = blockIdx.x * blockDim.x + threadIdx.x;
    int w = gid >> 6, lane = gid & 63;
    if (w >= N) return;
    int beg = rowptr[w], end = rowptr[w + 1];
    float s0 = 0.f, s1 = 0.f, s2 = 0.f, s3 = 0.f;
    int k = beg;
    for (; k + 2 <= end; k += 2) {
        int ca = col[k], cb = col[k + 1];
        ushort4 va = *((const ushort4*)(src + (size_t)ca * 256) + lane);
        ushort4 vb = *((const ushort4*)(src + (size_t)cb * 256) + lane);
        s0 += bf2f(va.x) + bf2f(vb.x);
        s1 += bf2f(va.y) + bf2f(vb.y);
        s2 += bf2f(va.z) + bf2f(vb.z);
        s3 += bf2f(va.w) + bf2f(vb.w);
    }
    if (k < end) {
        ushort4 v = *((const ushort4*)(src + (size_t)col[k] * 256) + lane);
        s0 += bf2f(v.x); s1 += bf2f(v.y); s2 += bf2f(v.z); s3 += bf2f(v.w);
    }
    float inv = 1.0f / (float)max(end - beg, 1);
    ushort4 o;
    o.x = f2bf(s0 * inv); o.y = f2bf(s1 * inv);
    o.z = f2bf(s2 * inv); o.w = f2bf(s3 * inv);
    *((ushort4*)(outt + (size_t)w * 256) + lane) = o;
}

// ---------------- agg of 64-col bf16 table, accumulate into fp32 out ------

__global__ void agg64_add_kernel(const ushort* __restrict__ Z,
                                 const int* __restrict__ rowptr,
                                 const int* __restrict__ col,
                                 float* __restrict__ out, int N) {
    int gid = blockIdx.x * blockDim.x + threadIdx.x;
    int w = gid >> 6, lane = gid & 63;
    if (w >= N) return;
    int beg = rowptr[w], end = rowptr[w + 1];
    float sa = 0.f, sb = 0.f;
    int k = beg;
    for (; k + 2 <= end; k += 2) {
        sa += bf2f(Z[(size_t)col[k] * 64 + lane]);
        sb += bf2f(Z[(size_t)col[k + 1] * 64 + lane]);
    }
    if (k < end) sa += bf2f(Z[(size_t)col[k] * 64 + lane]);
    float inv = 1.0f / (float)max(end - beg, 1);
    out[(size_t)w * 64 + lane] += (sa + sb) * inv;
}

// ---------------- A-streaming / W-in-LDS MFMA GEMM ----------------
// C[strip m0..m0+127, 128 cols] = [A1|A2] @ Wcat-block + bias (+relu).
// W chunk (128n x 256k = 67.6KB LDS, 2 blocks/CU) staged per kc; K-loop:
// B from LDS (b128, 2-way banks = free), A global->VGPR w/ 1-step prefetch,
// 16 MFMA/k-step. K1/K2 compile-time -> A1/A2 select folds per unrolled iter.
// MODE 0: y=layer (A cols y*128, W rows y*128, out cols y*128; relu+bias)
// MODE 1: y=n-half (A full,   W rows y*128, out cols y*128; relu+bias)
// MODE 2: y=0; cols 0..63 -> D bf16 (Z), 64..127 -> D2 fp32 + bias.
template <int K1, int K2, int MODE>
__global__ __launch_bounds__(256) void rs2_gemm_kernel(
    const ushort* __restrict__ A1, const ushort* __restrict__ A2, int lda,
    const ushort* __restrict__ Wg, const float* __restrict__ bias,
    ushort* __restrict__ D, float* __restrict__ D2, int M) {
    constexpr int KTOT = K1 + K2;
    constexpr int NCHUNK = KTOT / 256;
    constexpr int PK = 264;
    __shared__ __align__(16) ushort Bs[128 * PK];

    int y = blockIdx.y;
    if (MODE == 0) { A1 += y * 128; A2 += y * 128; }
    if (MODE != 2) {
        Wg += (size_t)y * 128 * KTOT;
        bias += y * 128;
        D += y * 128;
    }

    int tid = threadIdx.x;
    int m0 = blockIdx.x * 128;
    int wave = tid >> 6, lane = tid & 63;
    int lr = lane & 15, lq = lane >> 4;

    // row indices this wave's two m-tiles load (clamped; stores are guarded)
    int mrow[2];
#pragma unroll
    for (int mt = 0; mt < 2; ++mt)
        mrow[mt] = min(m0 + wave * 32 + mt * 16 + lr, M - 1);

    f32x4 acc[2][8];
#pragma unroll
    for (int i = 0; i < 2; ++i)
#pragma unroll
        for (int j = 0; j < 8; ++j) acc[i][j] = (f32x4){0.f, 0.f, 0.f, 0.f};

    auto loadA = [&](int kp, short8* a) {  // kp = global k' (compile-time per iter)
#pragma unroll
        for (int mt = 0; mt < 2; ++mt) {
            const ushort* srcp = (K2 == 0 || kp < K1)
                                     ? (A1 + (size_t)mrow[mt] * lda + kp)
                                     : (A2 + (size_t)mrow[mt] * lda + (kp - K1));
            a[mt] = *(const short8*)(srcp + lq * 8);
        }
    };

#pragma unroll
    for (int kc = 0; kc < NCHUNK; ++kc) {
        if (kc) __syncthreads();  // all waves done reading previous chunk
        // ---- stage W chunk: 128 rows x 256 cols, linear-coalesced ----
#pragma unroll
        for (int i = 0; i < 16; ++i) {
            int e = (tid + i * 256) * 8;       // elem in 128x256 chunk
            int row = e >> 8, colc = e & 255;
            float4 v = *(const float4*)(Wg + (size_t)row * KTOT + kc * 256 + colc);
            *(float4*)&Bs[row * PK + colc] = v;
        }
        __syncthreads();

        short8 acur[2], anx[2];
        loadA(kc * 256, acur);
#pragma unroll
        for (int ks = 0; ks < 8; ++ks) {
            if (ks < 7) loadA(kc * 256 + (ks + 1) * 32, anx);
            short8 b[8];
#pragma unroll
            for (int nt = 0; nt < 8; ++nt)
                b[nt] = *(const short8*)&Bs[(nt * 16 + lr) * PK + ks * 32 + lq * 8];
#pragma unroll
            for (int nt = 0; nt < 8; ++nt) {
                acc[0][nt] = __builtin_amdgcn_mfma_f32_16x16x32_bf16(
                    acur[0], b[nt], acc[0][nt], 0, 0, 0);
                acc[1][nt] = __builtin_amdgcn_mfma_f32_16x16x32_bf16(
                    acur[1], b[nt], acc[1][nt], 0, 0, 0);
            }
            acur[0] = anx[0];
            acur[1] = anx[1];
        }
    }

    // epilogue: C/D layout col = lane&15, row = (lane>>4)*4 + reg  [m89]
#pragma unroll
    for (int nt = 0; nt < 8; ++nt) {
        int c = nt * 16 + lr;
#pragma unroll
        for (int mt = 0; mt < 2; ++mt) {
#pragma unroll
            for (int r = 0; r < 4; ++r) {
                int m = m0 + wave * 32 + mt * 16 + lq * 4 + r;
                if (m >= M) continue;
                float v = acc[mt][nt][r];
                if (MODE == 2) {
                    if (c < 64) D[(size_t)m * 64 + c] = f2bf(v);
                    else        D2[(size_t)m * 64 + (c - 64)] = v + bias[c - 64];
                } else {
                    v = fmaxf(v + bias[c], 0.f);
                    D[(size_t)m * 256 + c] = f2bf(v);
                }
            }
        }
    }
}

// ---------------------------------------------------------------------------

extern "C" void kernel_launch(void* const* d_in, const int* in_sizes, int n_in,
                              void* d_out, int out_size, void* d_ws, size_t ws_size,
                              hipStream_t stream) {
    const float* x0 = (const float*)d_in[0];
    const float* x1 = (const float*)d_in[1];
    const int* ei = (const int*)d_in[2];  // integer inputs arrive as int32
    const float* Wl0 = (const float*)d_in[3];
    const float* Wr0 = (const float*)d_in[4];
    const float* b0 = (const float*)d_in[5];
    const float* Wl1 = (const float*)d_in[6];
    const float* Wr1 = (const float*)d_in[7];
    const float* b1 = (const float*)d_in[8];
    const float* Wlm = (const float*)d_in[9];
    const float* Wrm = (const float*)d_in[10];
    const float* bm = (const float*)d_in[11];
    const float* Wlo = (const float*)d_in[12];
    const float* Wro = (const float*)d_in[13];
    const float* bo = (const float*)d_in[14];

    const int N = in_sizes[0] / 128;
    const int E = in_sizes[2] / 2;
    const int* srcI = ei;
    const int* dstI = ei + E;

    // activation buffers aliased onto the (restored-each-call) input buffers
    ushort* xc  = (ushort*)d_in[0];  // [N,256] bf16 over x0's fp32 buf
    ushort* hb  = (ushort*)d_in[1];  // [N,256] bf16 over x1's buf
    ushort* hmb = (ushort*)d_in[0];  // [N,256] bf16 over xc (dead post-L0/L1)
    float* out = (float*)d_out;

    // ---- ws carve ----
    char* ws = (char*)d_ws;
    size_t used = 0;
    auto carve = [&](size_t bytes) {
        char* p = ws + used;
        used += (bytes + 63) & ~(size_t)63;
        return p;
    };
    int* deg = (int*)carve((size_t)2 * N * 4);
    int* cursor = deg + N;
    int* csum = (int*)carve(1024 * 4);
    int* coff = (int*)carve(1024 * 4);
    int* rowptr = (int*)carve((size_t)(N + 1) * 4);
    int* col = (int*)carve((size_t)E * 4);
    ushort* aggb = (ushort*)carve((size_t)N * 256 * 2);
    ushort* Zb   = (ushort*)carve((size_t)N * 64 * 2);
    ushort* Wcat1 = (ushort*)carve(256 * 256 * 2);
    ushort* Wcat2 = (ushort*)carve(256 * 512 * 2);
    ushort* Wcat3 = (ushort*)carve(128 * 256 * 2);
    float* bcat01 = (float*)carve(256 * 4);
    if (used > ws_size) return;  // fail clean, not with a mem fault

    const int CH = (N + 1023) / 1024;
    const int eb = (E + 255) / 256;
    const int ab = (N * 64 + 255) / 256;   // wave-per-node grid
    const int gb = (N + 127) / 128;        // GEMM 128-row strips
    const ushort* UN = nullptr;

    // ---- CSR ----
    hipMemsetAsync(deg, 0, (size_t)2 * N * 4, stream);
    deg_kernel<<<eb, 256, 0, stream>>>(dstI, deg, E);
    chunk_sum_kernel<<<4, 256, 0, stream>>>(deg, csum, N, CH);
    scan1024_kernel<<<1, 1024, 0, stream>>>(csum, coff);
    rowptr_kernel<<<4, 256, 0, stream>>>(deg, coff, rowptr, N, CH, E);
    scatter_kernel<<<eb, 256, 0, stream>>>(srcI, dstI, rowptr, cursor, col, E);

    // ---- conversions ----
    conv_x_kernel<<<ab, 256, 0, stream>>>(x0, x1, xc, N);
    conv_w_all_kernel<<<(65536 + 131072 + 32768 + 256 + 255) / 256, 256, 0, stream>>>(
        Wl0, Wr0, Wl1, Wr1, Wlm, Wrm, Wlo, Wro, b0, b1,
        Wcat1, Wcat2, Wcat3, bcat01);

    // ---- layer 0+1: h = relu([agg(xc)|xc] @ Wcat1 + bcat), y = layer ----
    agg_bf16_kernel<<<ab, 256, 0, stream>>>(xc, rowptr, col, aggb, N);
    rs2_gemm_kernel<128, 128, 0><<<dim3(gb, 2), 256, 0, stream>>>(
        aggb, xc, 256, Wcat1, bcat01, hb, nullptr, N);

    // ---- middle conv: hm = relu([agg(h)|h] @ Wcat2 + bm), y = n-half ----
    agg_bf16_kernel<<<ab, 256, 0, stream>>>(hb, rowptr, col, aggb, N);
    rs2_gemm_kernel<256, 256, 1><<<dim3(gb, 2), 256, 0, stream>>>(
        aggb, hb, 256, Wcat2, bm, hmb, nullptr, N);

    // ---- final conv (commuted): Z = hm@Wlo (bf16), out = hm@Wro + bo ----
    rs2_gemm_kernel<256, 0, 2><<<dim3(gb, 1), 256, 0, stream>>>(
        hmb, UN, 256, Wcat3, bo, Zb, out, N);
    agg64_add_kernel<<<ab, 256, 0, stream>>>(Zb, rowptr, col, out, N);
}

// Round 9
// 462.652 us; speedup vs baseline: 1.4213x; 1.0541x over previous
//
#include <hip/hip_runtime.h>
#include <cstdint>
#include <cstddef>

// ---------------------------------------------------------------------------
// LASAGE R9: MLP/occupancy push on the R8 structure.
//   - agg unroll x4 (4 gathers in flight per wave).
//   - GEMM: W-chunks 128n x 128k (34.8 KB LDS -> 4 blocks/CU, 16 waves/CU),
//     A global->VGPR with chunk-crossing 1-step prefetch.
//   - agg64 unroll x4; conv_x+conv_w fused into one dispatch.
//   - Structure otherwise identical to R8 (verified).
// ---------------------------------------------------------------------------

typedef __attribute__((ext_vector_type(8))) short short8;   // 8 x bf16
typedef __attribute__((ext_vector_type(4))) float f32x4;    // MFMA acc

__device__ __forceinline__ ushort f2bf(float f) {
    unsigned u = __float_as_uint(f);
    u += 0x7fffu + ((u >> 16) & 1u);   // round-to-nearest-even
    return (ushort)(u >> 16);
}
__device__ __forceinline__ float bf2f(ushort u) {
    return __uint_as_float((unsigned)u << 16);
}

// ---------------- CSR construction (verified R3-R8) ----------------

__global__ void deg_kernel(const int* __restrict__ dst, int* __restrict__ deg, int E) {
    int i = blockIdx.x * blockDim.x + threadIdx.x;
    if (i < E) atomicAdd(&deg[dst[i]], 1);
}

__global__ void chunk_sum_kernel(const int* __restrict__ deg,
                                 int* __restrict__ csum, int N, int CH) {
    int t = blockIdx.x * blockDim.x + threadIdx.x;
    int beg = t * CH, end = min(beg + CH, N);
    int s = 0;
    for (int i = beg; i < end; ++i) s += deg[i];
    csum[t] = s;
}

__global__ void scan1024_kernel(const int* __restrict__ csum, int* __restrict__ coff) {
    __shared__ int sh[1024];
    int t = threadIdx.x;
    int v0 = csum[t];
    sh[t] = v0;
    __syncthreads();
    for (int off = 1; off < 1024; off <<= 1) {
        int v = (t >= off) ? sh[t - off] : 0;
        __syncthreads();
        sh[t] += v;
        __syncthreads();
    }
    coff[t] = sh[t] - v0;
}

__global__ void rowptr_kernel(const int* __restrict__ deg, const int* __restrict__ coff,
                              int* __restrict__ rowptr, int N, int CH, int E) {
    int t = blockIdx.x * blockDim.x + threadIdx.x;
    int beg = t * CH, end = min(beg + CH, N);
    int run = coff[t];
    for (int i = beg; i < end; ++i) { rowptr[i] = run; run += deg[i]; }
    if (t == 0) rowptr[N] = E;
}

__global__ void scatter_kernel(const int* __restrict__ src, const int* __restrict__ dst,
                               const int* __restrict__ rowptr, int* __restrict__ cursor,
                               int* __restrict__ col, int E) {
    int i = blockIdx.x * blockDim.x + threadIdx.x;
    if (i < E) {
        int d = dst[i];
        int pos = atomicAdd(&cursor[d], 1);
        col[rowptr[d] + pos] = src[i];
    }
}

// ---------------- fused conversions (x -> bf16 concat; weights -> Wcat) ----
// Blocks [0, xb): xc[n][0:128]=bf16(x0[n]), [128:256]=bf16(x1[n]) (in-place
// over x0's buffer; no __restrict__ so loads stay ordered before stores).
// Blocks [xb, ...): build Wcat1 [256][256], Wcat2 [256][512], Wcat3 [128][256]
// (k-major, per-layer concat) and bcat01[256] = [b0|b1].
__global__ void conv_fused_kernel(
    const float* x0, const float* x1, ushort* xc, int N, int xb,
    const float* __restrict__ Wl0, const float* __restrict__ Wr0,
    const float* __restrict__ Wl1, const float* __restrict__ Wr1,
    const float* __restrict__ Wlm, const float* __restrict__ Wrm,
    const float* __restrict__ Wlo, const float* __restrict__ Wro,
    const float* __restrict__ b0, const float* __restrict__ b1,
    ushort* __restrict__ Wcat1, ushort* __restrict__ Wcat2,
    ushort* __restrict__ Wcat3, float* __restrict__ bcat01) {
    if (blockIdx.x < xb) {
        int gid = blockIdx.x * blockDim.x + threadIdx.x;
        int w = gid >> 6, lane = gid & 63;
        if (w >= N) return;
        float2 a = *((const float2*)(x0 + (size_t)w * 128) + lane);
        float2 b = *((const float2*)(x1 + (size_t)w * 128) + lane);
        ushort2 ua; ua.x = f2bf(a.x); ua.y = f2bf(a.y);
        ushort2 ub; ub.x = f2bf(b.x); ub.y = f2bf(b.y);
        *((ushort2*)(xc + (size_t)w * 256) + lane) = ua;
        *((ushort2*)(xc + (size_t)w * 256 + 128) + lane) = ub;
        return;
    }
    int idx = (blockIdx.x - xb) * blockDim.x + threadIdx.x;
    if (idx < 65536) {                       // Wcat1
        int n = idx >> 8, k = idx & 255;
        int half = n >> 7, nl = n & 127;
        const float* Wl = half ? Wl1 : Wl0;
        const float* Wr = half ? Wr1 : Wr0;
        float v = (k < 128) ? Wl[(size_t)k * 128 + nl]
                            : Wr[(size_t)(k - 128) * 128 + nl];
        Wcat1[idx] = f2bf(v);
    } else if (idx < 65536 + 131072) {       // Wcat2
        int i2 = idx - 65536;
        int n = i2 >> 9, k = i2 & 511;
        float v = (k < 256) ? Wlm[(size_t)k * 256 + n]
                            : Wrm[(size_t)(k - 256) * 256 + n];
        Wcat2[i2] = f2bf(v);
    } else if (idx < 65536 + 131072 + 32768) {  // Wcat3
        int i3 = idx - (65536 + 131072);
        int n = i3 >> 8, k = i3 & 255;
        float v = (n < 64) ? Wlo[(size_t)k * 64 + n]
                           : Wro[(size_t)k * 64 + (n - 64)];
        Wcat3[i3] = f2bf(v);
    } else if (idx < 65536 + 131072 + 32768 + 256) {  // bcat01
        int i4 = idx - (65536 + 131072 + 32768);
        bcat01[i4] = (i4 < 128) ? b0[i4] : b1[i4 - 128];
    }
}

// ---------------- aggregation: wave per node, 256 bf16 cols, unroll x4 ----

__global__ void agg_bf16_kernel(const ushort* __restrict__ src,
                                const int* __restrict__ rowptr,
                                const int* __restrict__ col,
                                ushort* __restrict__ outt, int N) {
    int gid = blockIdx.x * blockDim.x + threadIdx.x;
    int w = gid >> 6, lane = gid & 63;
    if (w >= N) return;
    int beg = rowptr[w], end = rowptr[w + 1];
    float s0 = 0.f, s1 = 0.f, s2 = 0.f, s3 = 0.f;
    int k = beg;
    for (; k + 4 <= end; k += 4) {
        int c0 = col[k], c1 = col[k + 1], c2 = col[k + 2], c3 = col[k + 3];
        ushort4 v0 = *((const ushort4*)(src + (size_t)c0 * 256) + lane);
        ushort4 v1 = *((const ushort4*)(src + (size_t)c1 * 256) + lane);
        ushort4 v2 = *((const ushort4*)(src + (size_t)c2 * 256) + lane);
        ushort4 v3 = *((const ushort4*)(src + (size_t)c3 * 256) + lane);
        s0 += bf2f(v0.x) + bf2f(v1.x) + bf2f(v2.x) + bf2f(v3.x);
        s1 += bf2f(v0.y) + bf2f(v1.y) + bf2f(v2.y) + bf2f(v3.y);
        s2 += bf2f(v0.z) + bf2f(v1.z) + bf2f(v2.z) + bf2f(v3.z);
        s3 += bf2f(v0.w) + bf2f(v1.w) + bf2f(v2.w) + bf2f(v3.w);
    }
    for (; k < end; ++k) {
        ushort4 v = *((const ushort4*)(src + (size_t)col[k] * 256) + lane);
        s0 += bf2f(v.x); s1 += bf2f(v.y); s2 += bf2f(v.z); s3 += bf2f(v.w);
    }
    float inv = 1.0f / (float)max(end - beg, 1);
    ushort4 o;
    o.x = f2bf(s0 * inv); o.y = f2bf(s1 * inv);
    o.z = f2bf(s2 * inv); o.w = f2bf(s3 * inv);
    *((ushort4*)(outt + (size_t)w * 256) + lane) = o;
}

// ---------------- agg of 64-col bf16 table, accumulate into fp32 out ------

__global__ void agg64_add_kernel(const ushort* __restrict__ Z,
                                 const int* __restrict__ rowptr,
                                 const int* __restrict__ col,
                                 float* __restrict__ out, int N) {
    int gid = blockIdx.x * blockDim.x + threadIdx.x;
    int w = gid >> 6, lane = gid & 63;
    if (w >= N) return;
    int beg = rowptr[w], end = rowptr[w + 1];
    float sa = 0.f, sb = 0.f, sc = 0.f, sd = 0.f;
    int k = beg;
    for (; k + 4 <= end; k += 4) {
        sa += bf2f(Z[(size_t)col[k] * 64 + lane]);
        sb += bf2f(Z[(size_t)col[k + 1] * 64 + lane]);
        sc += bf2f(Z[(size_t)col[k + 2] * 64 + lane]);
        sd += bf2f(Z[(size_t)col[k + 3] * 64 + lane]);
    }
    for (; k < end; ++k) sa += bf2f(Z[(size_t)col[k] * 64 + lane]);
    float inv = 1.0f / (float)max(end - beg, 1);
    out[(size_t)w * 64 + lane] += (sa + sb + sc + sd) * inv;
}

// ---------------- A-streaming / W-in-LDS MFMA GEMM (128k chunks) ----------
// C[strip m0..m0+127, 128 cols] = [A1|A2] @ Wcat-block + bias (+relu).
// W chunk (128n x 128k, 34.8 KB LDS -> 4 blocks/CU); B from LDS (b128),
// A global->VGPR with 1-step prefetch that crosses chunk boundaries.
// MODE 0: y=layer (A cols y*128, W rows y*128, out cols y*128; relu+bias)
// MODE 1: y=n-half (A full,   W rows y*128, out cols y*128; relu+bias)
// MODE 2: y=0; cols 0..63 -> D bf16 (Z), 64..127 -> D2 fp32 + bias.
template <int K1, int K2, int MODE>
__global__ __launch_bounds__(256) void rs2_gemm_kernel(
    const ushort* __restrict__ A1, const ushort* __restrict__ A2, int lda,
    const ushort* __restrict__ Wg, const float* __restrict__ bias,
    ushort* __restrict__ D, float* __restrict__ D2, int M) {
    constexpr int KTOT = K1 + K2;
    constexpr int NCHUNK = KTOT / 128;
    constexpr int PK = 136;
    __shared__ __align__(16) ushort Bs[128 * PK];

    int y = blockIdx.y;
    if (MODE == 0) { A1 += y * 128; A2 += y * 128; }
    if (MODE != 2) {
        Wg += (size_t)y * 128 * KTOT;
        bias += y * 128;
        D += y * 128;
    }

    int tid = threadIdx.x;
    int m0 = blockIdx.x * 128;
    int wave = tid >> 6, lane = tid & 63;
    int lr = lane & 15, lq = lane >> 4;

    // row indices this wave's two m-tiles load (clamped; stores are guarded)
    int mrow[2];
#pragma unroll
    for (int mt = 0; mt < 2; ++mt)
        mrow[mt] = min(m0 + wave * 32 + mt * 16 + lr, M - 1);

    f32x4 acc[2][8];
#pragma unroll
    for (int i = 0; i < 2; ++i)
#pragma unroll
        for (int j = 0; j < 8; ++j) acc[i][j] = (f32x4){0.f, 0.f, 0.f, 0.f};

    auto loadA = [&](int kp, short8* a) {  // kp = global k' (compile-time)
#pragma unroll
        for (int mt = 0; mt < 2; ++mt) {
            const ushort* srcp = (K2 == 0 || kp < K1)
                                     ? (A1 + (size_t)mrow[mt] * lda + kp)
                                     : (A2 + (size_t)mrow[mt] * lda + (kp - K1));
            a[mt] = *(const short8*)(srcp + lq * 8);
        }
    };

    short8 acur[2], anx[2];
    loadA(0, acur);

#pragma unroll
    for (int kc = 0; kc < NCHUNK; ++kc) {
        if (kc) __syncthreads();  // waves done reading previous chunk
        // ---- stage W chunk: 128 rows x 128 cols ----
#pragma unroll
        for (int i = 0; i < 8; ++i) {
            int e = (tid + i * 256) * 8;       // elem in 128x128 chunk
            int row = e >> 7, colc = e & 127;
            float4 v = *(const float4*)(Wg + (size_t)row * KTOT + kc * 128 + colc);
            *(float4*)&Bs[row * PK + colc] = v;
        }
        __syncthreads();

#pragma unroll
        for (int ks = 0; ks < 4; ++ks) {
            int kpn = kc * 128 + (ks + 1) * 32;   // next frag (may cross chunk)
            if (kpn < KTOT) loadA(kpn, anx);
            short8 b[8];
#pragma unroll
            for (int nt = 0; nt < 8; ++nt)
                b[nt] = *(const short8*)&Bs[(nt * 16 + lr) * PK + ks * 32 + lq * 8];
#pragma unroll
            for (int nt = 0; nt < 8; ++nt) {
                acc[0][nt] = __builtin_amdgcn_mfma_f32_16x16x32_bf16(
                    acur[0], b[nt], acc[0][nt], 0, 0, 0);
                acc[1][nt] = __builtin_amdgcn_mfma_f32_16x16x32_bf16(
                    acur[1], b[nt], acc[1][nt], 0, 0, 0);
            }
            acur[0] = anx[0];
            acur[1] = anx[1];
        }
    }

    // epilogue: C/D layout col = lane&15, row = (lane>>4)*4 + reg  [m89]
#pragma unroll
    for (int nt = 0; nt < 8; ++nt) {
        int c = nt * 16 + lr;
#pragma unroll
        for (int mt = 0; mt < 2; ++mt) {
#pragma unroll
            for (int r = 0; r < 4; ++r) {
                int m = m0 + wave * 32 + mt * 16 + lq * 4 + r;
                if (m >= M) continue;
                float v = acc[mt][nt][r];
                if (MODE == 2) {
                    if (c < 64) D[(size_t)m * 64 + c] = f2bf(v);
                    else        D2[(size_t)m * 64 + (c - 64)] = v + bias[c - 64];
                } else {
                    v = fmaxf(v + bias[c], 0.f);
                    D[(size_t)m * 256 + c] = f2bf(v);
                }
            }
        }
    }
}

// ---------------------------------------------------------------------------

extern "C" void kernel_launch(void* const* d_in, const int* in_sizes, int n_in,
                              void* d_out, int out_size, void* d_ws, size_t ws_size,
                              hipStream_t stream) {
    const float* x0 = (const float*)d_in[0];
    const float* x1 = (const float*)d_in[1];
    const int* ei = (const int*)d_in[2];  // integer inputs arrive as int32
    const float* Wl0 = (const float*)d_in[3];
    const float* Wr0 = (const float*)d_in[4];
    const float* b0 = (const float*)d_in[5];
    const float* Wl1 = (const float*)d_in[6];
    const float* Wr1 = (const float*)d_in[7];
    const float* b1 = (const float*)d_in[8];
    const float* Wlm = (const float*)d_in[9];
    const float* Wrm = (const float*)d_in[10];
    const float* bm = (const float*)d_in[11];
    const float* Wlo = (const float*)d_in[12];
    const float* Wro = (const float*)d_in[13];
    const float* bo = (const float*)d_in[14];

    const int N = in_sizes[0] / 128;
    const int E = in_sizes[2] / 2;
    const int* srcI = ei;
    const int* dstI = ei + E;

    // activation buffers aliased onto the (restored-each-call) input buffers
    ushort* xc  = (ushort*)d_in[0];  // [N,256] bf16 over x0's fp32 buf
    ushort* hb  = (ushort*)d_in[1];  // [N,256] bf16 over x1's buf
    ushort* hmb = (ushort*)d_in[0];  // [N,256] bf16 over xc (dead post-L0/L1)
    float* out = (float*)d_out;

    // ---- ws carve ----
    char* ws = (char*)d_ws;
    size_t used = 0;
    auto carve = [&](size_t bytes) {
        char* p = ws + used;
        used += (bytes + 63) & ~(size_t)63;
        return p;
    };
    int* deg = (int*)carve((size_t)2 * N * 4);
    int* cursor = deg + N;
    int* csum = (int*)carve(1024 * 4);
    int* coff = (int*)carve(1024 * 4);
    int* rowptr = (int*)carve((size_t)(N + 1) * 4);
    int* col = (int*)carve((size_t)E * 4);
    ushort* aggb = (ushort*)carve((size_t)N * 256 * 2);
    ushort* Zb   = (ushort*)carve((size_t)N * 64 * 2);
    ushort* Wcat1 = (ushort*)carve(256 * 256 * 2);
    ushort* Wcat2 = (ushort*)carve(256 * 512 * 2);
    ushort* Wcat3 = (ushort*)carve(128 * 256 * 2);
    float* bcat01 = (float*)carve(256 * 4);
    if (used > ws_size) return;  // fail clean, not with a mem fault

    const int CH = (N + 1023) / 1024;
    const int eb = (E + 255) / 256;
    const int ab = (N * 64 + 255) / 256;   // wave-per-node grid
    const int wb = (229632 + 255) / 256;   // weight-conversion blocks
    const int gb = (N + 127) / 128;        // GEMM 128-row strips
    const ushort* UN = nullptr;

    // ---- CSR ----
    hipMemsetAsync(deg, 0, (size_t)2 * N * 4, stream);
    deg_kernel<<<eb, 256, 0, stream>>>(dstI, deg, E);
    chunk_sum_kernel<<<4, 256, 0, stream>>>(deg, csum, N, CH);
    scan1024_kernel<<<1, 1024, 0, stream>>>(csum, coff);
    rowptr_kernel<<<4, 256, 0, stream>>>(deg, coff, rowptr, N, CH, E);
    scatter_kernel<<<eb, 256, 0, stream>>>(srcI, dstI, rowptr, cursor, col, E);

    // ---- conversions (fused) ----
    conv_fused_kernel<<<ab + wb, 256, 0, stream>>>(
        x0, x1, xc, N, ab,
        Wl0, Wr0, Wl1, Wr1, Wlm, Wrm, Wlo, Wro, b0, b1,
        Wcat1, Wcat2, Wcat3, bcat01);

    // ---- layer 0+1: h = relu([agg(xc)|xc] @ Wcat1 + bcat), y = layer ----
    agg_bf16_kernel<<<ab, 256, 0, stream>>>(xc, rowptr, col, aggb, N);
    rs2_gemm_kernel<128, 128, 0><<<dim3(gb, 2), 256, 0, stream>>>(
        aggb, xc, 256, Wcat1, bcat01, hb, nullptr, N);

    // ---- middle conv: hm = relu([agg(h)|h] @ Wcat2 + bm), y = n-half ----
    agg_bf16_kernel<<<ab, 256, 0, stream>>>(hb, rowptr, col, aggb, N);
    rs2_gemm_kernel<256, 256, 1><<<dim3(gb, 2), 256, 0, stream>>>(
        aggb, hb, 256, Wcat2, bm, hmb, nullptr, N);

    // ---- final conv (commuted): Z = hm@Wlo (bf16), out = hm@Wro + bo ----
    rs2_gemm_kernel<256, 0, 2><<<dim3(gb, 1), 256, 0, stream>>>(
        hmb, UN, 256, Wcat3, bo, Zb, out, N);
    agg64_add_kernel<<<ab, 256, 0, stream>>>(Zb, rowptr, col, out, N);
}